// Round 6
// baseline (1750.483 us; speedup 1.0000x reference)
//
#include <hip/hip_runtime.h>
#include <hip/hip_bf16.h>
#include <math.h>

// dtype resolved empirically: all float inputs fp32, output fp32.
// GEMMs run as bf16 MFMA (threshold 2.5e-2 sized for bf16 compute; absmax 0.0078 @ R5).

#define DEV __device__ __forceinline__

typedef __bf16 bf16_t;
typedef __attribute__((ext_vector_type(8))) __bf16 bf16x8;
typedef __attribute__((ext_vector_type(4))) float f32x4;

DEV float siluf(float x){ return x / (1.f + expf(-x)); }
DEV float softplusf(float x){ return fmaxf(x, 0.f) + log1pf(expf(-fabsf(x))); }

// scan-order permutation: scan position l of direction k reads spatial row perm_idx(k,l)
DEV int perm_idx(int k, int l){
  switch(k & 3){
    case 0: return l;
    case 1: return 255 - l;
    case 2: return ((l & 15) << 4) | (l >> 4);
    default: { int r = 255 - l; return ((r & 15) << 4) | (r >> 4); }
  }
}

// ---------- per-layer weight fp32 -> bf16 cast ----------
// segments (elements): in_w 147456 | outp_w 147456 | mlp_w1 1179648 | mlp_w2 589824 | xproj 86016
__global__ void k_cvt_layer(const float* __restrict__ inw, const float* __restrict__ outw,
                            const float* __restrict__ w1, const float* __restrict__ w2,
                            const float* __restrict__ xp, bf16_t* __restrict__ dst){
  int idx = (blockIdx.x*256 + threadIdx.x)*4;   // 2150400 total
  const float* src; int off;
  if (idx < 147456){ src = inw;  off = idx; }
  else if (idx < 294912){ src = outw; off = idx - 147456; }
  else if (idx < 1474560){ src = w1; off = idx - 294912; }
  else if (idx < 2064384){ src = w2; off = idx - 1474560; }
  else { src = xp; off = idx - 2064384; }
  float4 v = *(const float4*)(src + off);
  union { bf16_t h[4]; uint2 u; } cv;
  cv.h[0] = (bf16_t)v.x; cv.h[1] = (bf16_t)v.y; cv.h[2] = (bf16_t)v.z; cv.h[3] = (bf16_t)v.w;
  *(uint2*)(dst + idx) = cv.u;
}

// ---------- conditioning ----------
__global__ void k_cond(const float* __restrict__ t, const int* __restrict__ y,
                       const float* __restrict__ tw1, const float* __restrict__ tb1,
                       const float* __restrict__ tw2, const float* __restrict__ tb2,
                       const float* __restrict__ ytab, float* __restrict__ sc){
  int b = blockIdx.x; int o = threadIdx.x;  // block 384
  __shared__ float temb[256]; __shared__ float h1[384];
  float tv = t[b];
  if (o < 128){
    float f = expf(-logf(10000.f) * (float)o / 128.f);
    float a = tv * f;
    temb[o] = cosf(a); temb[128 + o] = sinf(a);
  }
  __syncthreads();
  float acc = tb1[o];
  for (int j = 0; j < 256; j++) acc += temb[j] * tw1[(size_t)o*256 + j];
  h1[o] = siluf(acc);
  __syncthreads();
  float acc2 = tb2[o];
  for (int j = 0; j < 384; j++) acc2 += h1[j] * tw2[(size_t)o*384 + j];
  float c = acc2 + ytab[(size_t)y[b]*384 + o];
  sc[b*384 + o] = siluf(c);
}

// ---------- patch embed + pos embed ----------
__global__ void k_patch(const float* __restrict__ x, const float* __restrict__ pw1,
                        const float* __restrict__ pw2, const float* __restrict__ pb2,
                        const float* __restrict__ pos, float* __restrict__ h){
  int bl = blockIdx.x; int b = bl >> 8; int l = bl & 255;
  int gh = l >> 4, gw = l & 15;
  __shared__ float xp[12]; __shared__ float tmp[128];
  int tid = threadIdx.x;  // block 384
  if (tid < 12){
    int ci = tid >> 2, ph = (tid >> 1) & 1, pw = tid & 1;
    xp[tid] = x[((size_t)(b*3 + ci)*32 + gh*2 + ph)*32 + gw*2 + pw];
  }
  __syncthreads();
  if (tid < 128){
    float a = 0.f;
    #pragma unroll
    for (int k = 0; k < 12; k++) a += xp[k] * pw1[tid*12 + k];
    tmp[tid] = a;
  }
  __syncthreads();
  float a = pb2[tid];
  for (int j = 0; j < 128; j++) a += tmp[j] * pw2[(size_t)tid*128 + j];
  h[(size_t)(b*256 + l)*384 + tid] = a + pos[(size_t)l*384 + tid];
}

// ---------- small linear ----------
__global__ void k_lin_small(const float* __restrict__ sc, const float* __restrict__ W,
                            const float* __restrict__ bias, float* __restrict__ out, int N){
  int idx = blockIdx.x * blockDim.x + threadIdx.x;
  if (idx >= 4*N) return;
  int b = idx / N, o = idx % N;
  const float4* cp = (const float4*)(sc + b*384);
  const float4* wp = (const float4*)(W + (size_t)o*384);
  float a = bias[o];
  #pragma unroll 4
  for (int k = 0; k < 96; k++){
    float4 c4 = cp[k], w4 = wp[k];
    a += c4.x*w4.x + c4.y*w4.y + c4.z*w4.z + c4.w*w4.w;
  }
  out[idx] = a;
}

// ---------- RMSNorm + adaLN modulate -> bf16 ----------
__global__ void k_rms_mod(const float* __restrict__ h, const float* __restrict__ nw,
                          const float* __restrict__ modBase, bf16_t* __restrict__ out){
  int bl = blockIdx.x; int b = bl >> 8;
  const float* hp = h + (size_t)bl*384;
  const float* mp = modBase + (size_t)b*18432;
  __shared__ float red[2];
  int tid = threadIdx.x;  // block 128
  float v[3]; float ss = 0.f;
  #pragma unroll
  for (int ii = 0; ii < 3; ii++){ v[ii] = hp[tid + ii*128]; ss += v[ii]*v[ii]; }
  #pragma unroll
  for (int off = 32; off; off >>= 1) ss += __shfl_down(ss, off);
  if ((tid & 63) == 0) red[tid >> 6] = ss;
  __syncthreads();
  ss = red[0] + red[1];
  float inv = rsqrtf(ss / 384.f + 1e-6f);
  #pragma unroll
  for (int ii = 0; ii < 3; ii++){
    int d = tid + ii*128;
    float xv = v[ii] * inv * nw[d];
    out[(size_t)bl*384 + d] = (bf16_t)(xv * (1.f + mp[384 + d]) + mp[d]);
  }
}

// ---------- bf16 MFMA GEMM: C[M,N] = A[M,K] @ W[N,K]^T ----------
// MODE 0: C = acc; MODE 1: C = acc + bias;
// MODE 2: C += gate*acc (gate = modBase[(row>>8)*18432 + col]);
// MODE 3: A-stage = bf16(silu(u1)*u2), A fp32 row stride 2K; C += gate*(acc+bias)
template<int MODE>
__global__ __launch_bounds__(256) void k_gemm_bf(
    const void* __restrict__ Avoid, const bf16_t* __restrict__ W,
    const float* __restrict__ bias, float* __restrict__ C,
    const float* __restrict__ modBase, int N, int K, int Nstore){
  __shared__ bf16_t As[2][64*40];
  __shared__ bf16_t Ws[2][64*40];
  const int tid = threadIdx.x;
  const int bm = blockIdx.y * 64, bn = blockIdx.x * 64;
  const int wave = tid >> 6, lane = tid & 63;
  const int m16 = lane & 15, kg = lane >> 4;
  const int r = tid >> 2, seg = tid & 3;
  const int nt = K / 32;

  uint4 aP, wP;
  auto loadT = [&](int kt){
    wP = *(const uint4*)(W + (size_t)(bn + r)*K + kt*32 + seg*8);
    if constexpr (MODE == 3){
      const float* Ap = (const float*)Avoid + (size_t)(bm + r)*(size_t)(2*K) + kt*32 + seg*8;
      float4 u1a = *(const float4*)(Ap),     u1b = *(const float4*)(Ap + 4);
      float4 u2a = *(const float4*)(Ap + K), u2b = *(const float4*)(Ap + K + 4);
      union { bf16_t h[8]; uint4 u; } pk;
      pk.h[0] = (bf16_t)(siluf(u1a.x)*u2a.x); pk.h[1] = (bf16_t)(siluf(u1a.y)*u2a.y);
      pk.h[2] = (bf16_t)(siluf(u1a.z)*u2a.z); pk.h[3] = (bf16_t)(siluf(u1a.w)*u2a.w);
      pk.h[4] = (bf16_t)(siluf(u1b.x)*u2b.x); pk.h[5] = (bf16_t)(siluf(u1b.y)*u2b.y);
      pk.h[6] = (bf16_t)(siluf(u1b.z)*u2b.z); pk.h[7] = (bf16_t)(siluf(u1b.w)*u2b.w);
      aP = pk.u;
    } else {
      aP = *(const uint4*)((const bf16_t*)Avoid + (size_t)(bm + r)*K + kt*32 + seg*8);
    }
  };
  auto stash = [&](int buf){
    *(uint4*)&As[buf][r*40 + seg*8] = aP;
    *(uint4*)&Ws[buf][r*40 + seg*8] = wP;
  };

  f32x4 acc[4] = {};
  loadT(0); stash(0); __syncthreads();
  for (int kt = 0; kt < nt; kt++){
    int buf = kt & 1;
    if (kt + 1 < nt) loadT(kt + 1);
    bf16x8 af = *(bf16x8*)&As[buf][(wave*16 + m16)*40 + kg*8];
    #pragma unroll
    for (int j = 0; j < 4; j++){
      bf16x8 bfr = *(bf16x8*)&Ws[buf][(j*16 + m16)*40 + kg*8];
      acc[j] = __builtin_amdgcn_mfma_f32_16x16x32_bf16(af, bfr, acc[j], 0, 0, 0);
    }
    if (kt + 1 < nt) stash(buf ^ 1);
    __syncthreads();
  }

  // C/D layout: col = lane&15, row = (lane>>4)*4 + reg
  #pragma unroll
  for (int j = 0; j < 4; j++){
    int col = bn + j*16 + m16;
    if (col < Nstore){
      #pragma unroll
      for (int rg = 0; rg < 4; rg++){
        int row = bm + wave*16 + kg*4 + rg;
        float v = acc[j][rg];
        if constexpr (MODE == 1 || MODE == 3) v += bias[col];
        if constexpr (MODE >= 2)
          C[(size_t)row*N + col] += modBase[(size_t)(row >> 8)*18432 + col] * v;
        else
          C[(size_t)row*N + col] = v;
      }
    }
  }
}

// ---------- depthwise 3x3 conv + bias + silu; writes fp32 + bf16 copies ----------
__global__ void k_conv(const float* __restrict__ z, const float* __restrict__ cw,
                       const float* __restrict__ cb, float* __restrict__ convT,
                       bf16_t* __restrict__ convB){
  int bl = blockIdx.x; int b = bl >> 8, l = bl & 255;
  int hh = l >> 4, ww = l & 15;
  int d = threadIdx.x;  // 384
  float acc = cb[d];
  #pragma unroll
  for (int kh = 0; kh < 3; kh++){
    int yy = hh + kh - 1; if ((unsigned)yy > 15u) continue;
    #pragma unroll
    for (int kw = 0; kw < 3; kw++){
      int xx = ww + kw - 1; if ((unsigned)xx > 15u) continue;
      acc += z[(size_t)(b*256 + yy*16 + xx)*384 + d] * cw[d*9 + kh*3 + kw];
    }
  }
  float s = siluf(acc);
  convT[(size_t)bl*384 + d] = s;
  convB[(size_t)bl*384 + d] = (bf16_t)s;
}

// ---------- dt precompute: dtPre[(b,k,lsp),d] = softplus(dtr . dt_w[k,d,:] + dt_b[k,d]) ----------
// xdblS layout: [b][lsp][224] cols k*56 + {dtr 0..23 | B 24..39 | C 40..55}
__global__ void k_dtpre(const float* __restrict__ xdblS, const float* __restrict__ dtw,
                        const float* __restrict__ dtb, float* __restrict__ dtPre){
  int blk = blockIdx.x;        // b*1024 + k*256 + lsp
  int lsp = blk & 255, k = (blk >> 8) & 3;
  int b = blk >> 10;
  int d = threadIdx.x;         // 384
  __shared__ float sdtr[24];
  if (d < 24) sdtr[d] = xdblS[((size_t)(b*256 + lsp))*224 + k*56 + d];
  __syncthreads();
  const float4* w = (const float4*)(dtw + ((size_t)k*384 + d)*24);
  float a = dtb[k*384 + d];
  #pragma unroll
  for (int r4 = 0; r4 < 6; r4++){
    float4 wv = w[r4];
    a += sdtr[r4*4+0]*wv.x + sdtr[r4*4+1]*wv.y + sdtr[r4*4+2]*wv.z + sdtr[r4*4+3]*wv.w;
  }
  dtPre[(size_t)blk*384 + d] = softplusf(a);
}

// ---------- chunked selective scan -> ysT[b,k,d,l_scan] (coalesced block write) ----------
__global__ __launch_bounds__(256) void k_scan(
    const float* __restrict__ xdblS, const float* __restrict__ convT,
    const float* __restrict__ dtPre,
    const float* __restrict__ Alog, const float* __restrict__ Dsw,
    float* __restrict__ ysT){
  int blk = blockIdx.x;                 // b*1536 + k*384 + d
  int d = blk % 384; int k = (blk / 384) & 3; int b = blk / 1536;
  int tid = threadIdx.x;
  int n = tid & 15, chunk = tid >> 4;
  __shared__ float sdt[256], sxv[256], sy[256];
  __shared__ float sA[16][17], sB[16][17], sPre[16][17];

  // phase 0: gather dt and x at scan order (1 load each)
  {
    int lp = perm_idx(k, tid);
    sdt[tid] = dtPre[((size_t)(b*1024 + k*256) + lp)*384 + d];
    sxv[tid] = convT[((size_t)(b*256 + lp))*384 + d];
  }
  __syncthreads();

  float a = -expf(Alog[((size_t)(k*384) + d)*16 + n]);
  float Dv = Dsw[k*384 + d];

  // phase 1: local chunk scan from zero state
  float dA[16], dBu[16];
  float Ap = 1.f, hloc = 0.f;
  #pragma unroll
  for (int i = 0; i < 16; i++){
    int l = chunk*16 + i;
    int lp = perm_idx(k, l);
    float dtv = sdt[l];
    float bn = xdblS[((size_t)(b*256 + lp))*224 + k*56 + 24 + n];
    float e = expf(dtv * a);
    float u = dtv * sxv[l] * bn;
    dA[i] = e; dBu[i] = u;
    Ap *= e; hloc = e*hloc + u;
  }
  sA[chunk][n] = Ap; sB[chunk][n] = hloc;
  __syncthreads();

  // phase 2: carry scan across 16 chunks
  if (tid < 16){
    float carry = 0.f;
    #pragma unroll
    for (int c = 0; c < 16; c++){
      sPre[c][tid] = carry;
      carry = sA[c][tid]*carry + sB[c][tid];
    }
  }
  __syncthreads();

  // phase 3: replay; reduce over n; stage into sy
  float h = sPre[chunk][n];
  #pragma unroll
  for (int i = 0; i < 16; i++){
    int l = chunk*16 + i;
    int lp = perm_idx(k, l);
    float cn = xdblS[((size_t)(b*256 + lp))*224 + k*56 + 40 + n];
    h = dA[i]*h + dBu[i];
    float p = h * cn;
    p += __shfl_xor(p, 1);
    p += __shfl_xor(p, 2);
    p += __shfl_xor(p, 4);
    p += __shfl_xor(p, 8);
    if (n == 0) sy[l] = p + Dv * sxv[l];
  }
  __syncthreads();
  // coalesced write: ysT[b,k,d,l]
  ysT[((size_t)(b*4 + k)*384 + d)*256 + tid] = sy[tid];
}

// ---------- merge 4 directions + LayerNorm(onorm) -> bf16 (ysT[b,k,d,l_scan]) ----------
__global__ void k_merge_ln(const float* __restrict__ ysT, const float* __restrict__ ow,
                           const float* __restrict__ ob, bf16_t* __restrict__ out){
  int bl = blockIdx.x; int b = bl >> 8; int l = bl & 255;
  int tl = ((l & 15) << 4) | (l >> 4);
  int i2 = 255 - l, i4 = 255 - tl;
  __shared__ float red[4];
  int tid = threadIdx.x;  // block 128
  const float* base = ysT + (size_t)b*4*384*256;
  float v[3]; float s = 0.f, s2 = 0.f;
  #pragma unroll
  for (int ii = 0; ii < 3; ii++){
    int d = tid + ii*128;
    float vv = base[(size_t)d*256 + l]
             + base[(size_t)(384 + d)*256 + i2]
             + base[(size_t)(768 + d)*256 + tl]
             + base[(size_t)(1152 + d)*256 + i4];
    v[ii] = vv; s += vv; s2 += vv*vv;
  }
  #pragma unroll
  for (int off = 32; off; off >>= 1){ s += __shfl_down(s, off); s2 += __shfl_down(s2, off); }
  if ((tid & 63) == 0){ red[tid >> 6] = s; red[2 + (tid >> 6)] = s2; }
  __syncthreads();
  s = red[0] + red[1]; s2 = red[2] + red[3];
  float mu = s / 384.f;
  float var = s2 / 384.f - mu*mu;
  float inv = rsqrtf(var + 1e-5f);
  #pragma unroll
  for (int ii = 0; ii < 3; ii++){
    int d = tid + ii*128;
    out[(size_t)bl*384 + d] = (bf16_t)((v[ii] - mu) * inv * ow[d] + ob[d]);
  }
}

// ---------- final: ln_na + modulate + f_lin + unpatchify ----------
__global__ void k_final(const float* __restrict__ h, const float* __restrict__ modf,
                        const float* __restrict__ flw, const float* __restrict__ flb,
                        float* __restrict__ out){
  int bl = blockIdx.x; int b = bl >> 8; int l = bl & 255;
  int tid = threadIdx.x;  // block 128
  __shared__ float buf[384]; __shared__ float red[4];
  const float* hp = h + (size_t)bl*384;
  float v[3]; float s = 0.f, s2 = 0.f;
  #pragma unroll
  for (int ii = 0; ii < 3; ii++){ float xv = hp[tid + ii*128]; v[ii] = xv; s += xv; s2 += xv*xv; }
  #pragma unroll
  for (int off = 32; off; off >>= 1){ s += __shfl_down(s, off); s2 += __shfl_down(s2, off); }
  if ((tid & 63) == 0){ red[tid >> 6] = s; red[2 + (tid >> 6)] = s2; }
  __syncthreads();
  s = red[0] + red[1]; s2 = red[2] + red[3];
  float mu = s / 384.f;
  float var = s2 / 384.f - mu*mu;
  float inv = rsqrtf(var + 1e-6f);
  #pragma unroll
  for (int ii = 0; ii < 3; ii++){
    int d = tid + ii*128;
    buf[d] = (v[ii] - mu) * inv * (1.f + modf[b*768 + 384 + d]) + modf[b*768 + d];
  }
  __syncthreads();
  if (tid < 12){
    float a = flb[tid];
    for (int k = 0; k < 384; k++) a += buf[k] * flw[(size_t)tid*384 + k];
    int p = tid / 6, q = (tid / 3) & 1, cc = tid % 3;
    int gh = l >> 4, gw = l & 15;
    out[((size_t)(b*3 + cc)*32 + gh*2 + p)*32 + gw*2 + q] = a;
  }
}

extern "C" void kernel_launch(void* const* d_in, const int* in_sizes, int n_in,
                              void* d_out, int out_size, void* d_ws, size_t ws_size,
                              hipStream_t stream){
  const float* x       = (const float*)d_in[0];
  const float* t       = (const float*)d_in[1];
  const int*   y       = (const int*)  d_in[2];
  const float* t_w1    = (const float*)d_in[3];
  const float* t_b1    = (const float*)d_in[4];
  const float* t_w2    = (const float*)d_in[5];
  const float* t_b2    = (const float*)d_in[6];
  const float* y_table = (const float*)d_in[7];
  const float* pe_w1   = (const float*)d_in[8];
  const float* pe_w2   = (const float*)d_in[9];
  const float* pe_b2   = (const float*)d_in[10];
  const float* pos     = (const float*)d_in[11];
  const float* adaln_w = (const float*)d_in[12];
  const float* adaln_b = (const float*)d_in[13];
  const float* n1_w    = (const float*)d_in[14];
  const float* n2_w    = (const float*)d_in[15];
  const float* in_w    = (const float*)d_in[16];
  const float* conv_w  = (const float*)d_in[17];
  const float* conv_b  = (const float*)d_in[18];
  const float* xproj_w = (const float*)d_in[19];
  const float* dt_w    = (const float*)d_in[20];
  const float* dt_b    = (const float*)d_in[21];
  const float* A_logs  = (const float*)d_in[22];
  const float* Ds      = (const float*)d_in[23];
  const float* onorm_w = (const float*)d_in[24];
  const float* onorm_b = (const float*)d_in[25];
  const float* outp_w  = (const float*)d_in[26];
  const float* mlp_w1  = (const float*)d_in[27];
  const float* mlp_b1  = (const float*)d_in[28];
  const float* mlp_w2  = (const float*)d_in[29];
  const float* mlp_b2  = (const float*)d_in[30];
  const float* f_adaln_w = (const float*)d_in[31];
  const float* f_adaln_b = (const float*)d_in[32];
  const float* f_lin_w = (const float*)d_in[33];
  const float* f_lin_b = (const float*)d_in[34];

  float* ws = (float*)d_ws;
  float*  sc      = ws + 0;         // 1536
  float*  h       = ws + 1536;      // 393216
  float*  modAll  = ws + 394752;    // 73728 (4 x 18432)
  float*  modf    = ws + 468480;    // 3072
  float*  buf1    = ws + 471552;    // 393216 (z)
  float*  convT   = ws + 864768;    // 393216
  float*  xdblS   = ws + 1257984;   // 229376 (4 x 256 x 224)
  float*  u12     = ws + 1487360;   // 3145728 (mlp intermediate; dtPre aliases first half)
  float*  dtPre   = u12;            // 1572864 — dead before u12 is written (gemm_w1)
  float*  ysT     = ws + 4633088;   // 1572864
  bf16_t* xin_bf  = (bf16_t*)(ws + 6205952);   // 393216 bf16
  bf16_t* ssin_bf = (bf16_t*)(ws + 6402560);   // 393216 bf16
  bf16_t* conv_bf = (bf16_t*)(ws + 6599168);   // 393216 bf16
  bf16_t* wbf     = (bf16_t*)(ws + 6795776);   // 2150400 bf16

  bf16_t* wbf_in = wbf;
  bf16_t* wbf_out = wbf + 147456;
  bf16_t* wbf_w1 = wbf + 294912;
  bf16_t* wbf_w2 = wbf + 1474560;
  bf16_t* wbf_xp = wbf + 2064384;

  k_cond<<<dim3(4), dim3(384), 0, stream>>>(t, y, t_w1, t_b1, t_w2, t_b2, y_table, sc);
  k_patch<<<dim3(1024), dim3(384), 0, stream>>>(x, pe_w1, pe_w2, pe_b2, pos, h);
  k_lin_small<<<dim3(288), dim3(256), 0, stream>>>(sc, adaln_w, adaln_b, modAll, 18432);

  for (int i = 0; i < 8; i++){
    const float* modL = modAll + (size_t)i*2304;
    k_cvt_layer<<<dim3(2100), dim3(256), 0, stream>>>(
        in_w + (size_t)i*147456, outp_w + (size_t)i*147456, mlp_w1 + (size_t)i*1179648,
        mlp_w2 + (size_t)i*589824, xproj_w + (size_t)i*86016, wbf);
    k_rms_mod<<<dim3(1024), dim3(128), 0, stream>>>(h, n1_w + i*384, modL + 0, xin_bf);
    k_gemm_bf<0><<<dim3(6,16), dim3(256), 0, stream>>>(
        xin_bf, wbf_in, nullptr, buf1, nullptr, 384, 384, 384);
    k_conv<<<dim3(1024), dim3(384), 0, stream>>>(
        buf1, conv_w + (size_t)i*384*9, conv_b + i*384, convT, conv_bf);
    k_gemm_bf<0><<<dim3(4,16), dim3(256), 0, stream>>>(
        conv_bf, wbf_xp, nullptr, xdblS, nullptr, 224, 384, 224);
    k_dtpre<<<dim3(4096), dim3(384), 0, stream>>>(
        xdblS, dt_w + (size_t)i*4*384*24, dt_b + (size_t)i*4*384, dtPre);
    k_scan<<<dim3(6144), dim3(256), 0, stream>>>(
        xdblS, convT, dtPre,
        A_logs + (size_t)i*4*384*16, Ds + (size_t)i*4*384, ysT);
    k_merge_ln<<<dim3(1024), dim3(128), 0, stream>>>(
        ysT, onorm_w + i*384, onorm_b + i*384, ssin_bf);
    k_gemm_bf<2><<<dim3(6,16), dim3(256), 0, stream>>>(
        ssin_bf, wbf_out, nullptr, h, modL + 768, 384, 384, 384);
    k_rms_mod<<<dim3(1024), dim3(128), 0, stream>>>(h, n2_w + i*384, modL + 1152, xin_bf);
    k_gemm_bf<1><<<dim3(48,16), dim3(256), 0, stream>>>(
        xin_bf, wbf_w1, mlp_b1 + (size_t)i*3072, u12, nullptr, 3072, 384, 3072);
    k_gemm_bf<3><<<dim3(6,16), dim3(256), 0, stream>>>(
        u12, wbf_w2, mlp_b2 + (size_t)i*384, h, modL + 1920, 384, 1536, 384);
  }

  k_lin_small<<<dim3(12), dim3(256), 0, stream>>>(sc, f_adaln_w, f_adaln_b, modf, 768);
  k_final<<<dim3(1024), dim3(128), 0, stream>>>(h, modf, f_lin_w, f_lin_b, (float*)d_out);
}

// Round 7
// 1588.864 us; speedup vs baseline: 1.1017x; 1.1017x over previous
//
#include <hip/hip_runtime.h>
#include <hip/hip_bf16.h>
#include <math.h>

// dtype resolved empirically: all float inputs fp32, output fp32.
// GEMMs run as bf16 MFMA (threshold 2.5e-2 sized for bf16 compute; absmax 0.0078 @ R5/R6).
// R6 lesson: dt must be computed inside the scan (dtPre global round-trip = 3.4x FETCH).

#define DEV __device__ __forceinline__

typedef __bf16 bf16_t;
typedef __attribute__((ext_vector_type(8))) __bf16 bf16x8;
typedef __attribute__((ext_vector_type(4))) float f32x4;

DEV float siluf(float x){ return x / (1.f + __expf(-x)); }
DEV float softplusf(float x){ return fmaxf(x, 0.f) + __logf(1.f + __expf(-fabsf(x))); }

// scan-order permutation: scan position l of direction k reads spatial row perm_idx(k,l)
DEV int perm_idx(int k, int l){
  switch(k & 3){
    case 0: return l;
    case 1: return 255 - l;
    case 2: return ((l & 15) << 4) | (l >> 4);
    default: { int r = 255 - l; return ((r & 15) << 4) | (r >> 4); }
  }
}

// ---------- per-layer weight fp32 -> bf16 cast ----------
// segments (elements): in_w 147456 | outp_w 147456 | mlp_w1 1179648 | mlp_w2 589824 | xproj 86016
__global__ void k_cvt_layer(const float* __restrict__ inw, const float* __restrict__ outw,
                            const float* __restrict__ w1, const float* __restrict__ w2,
                            const float* __restrict__ xp, bf16_t* __restrict__ dst){
  int idx = (blockIdx.x*256 + threadIdx.x)*4;   // 2150400 total
  const float* src; int off;
  if (idx < 147456){ src = inw;  off = idx; }
  else if (idx < 294912){ src = outw; off = idx - 147456; }
  else if (idx < 1474560){ src = w1; off = idx - 294912; }
  else if (idx < 2064384){ src = w2; off = idx - 1474560; }
  else { src = xp; off = idx - 2064384; }
  float4 v = *(const float4*)(src + off);
  union { bf16_t h[4]; uint2 u; } cv;
  cv.h[0] = (bf16_t)v.x; cv.h[1] = (bf16_t)v.y; cv.h[2] = (bf16_t)v.z; cv.h[3] = (bf16_t)v.w;
  *(uint2*)(dst + idx) = cv.u;
}

// ---------- conditioning ----------
__global__ void k_cond(const float* __restrict__ t, const int* __restrict__ y,
                       const float* __restrict__ tw1, const float* __restrict__ tb1,
                       const float* __restrict__ tw2, const float* __restrict__ tb2,
                       const float* __restrict__ ytab, float* __restrict__ sc){
  int b = blockIdx.x; int o = threadIdx.x;  // block 384
  __shared__ float temb[256]; __shared__ float h1[384];
  float tv = t[b];
  if (o < 128){
    float f = __expf(-logf(10000.f) * (float)o / 128.f);
    float a = tv * f;
    temb[o] = cosf(a); temb[128 + o] = sinf(a);
  }
  __syncthreads();
  float acc = tb1[o];
  for (int j = 0; j < 256; j++) acc += temb[j] * tw1[(size_t)o*256 + j];
  h1[o] = siluf(acc);
  __syncthreads();
  float acc2 = tb2[o];
  for (int j = 0; j < 384; j++) acc2 += h1[j] * tw2[(size_t)o*384 + j];
  float c = acc2 + ytab[(size_t)y[b]*384 + o];
  sc[b*384 + o] = siluf(c);
}

// ---------- patch embed + pos embed ----------
__global__ void k_patch(const float* __restrict__ x, const float* __restrict__ pw1,
                        const float* __restrict__ pw2, const float* __restrict__ pb2,
                        const float* __restrict__ pos, float* __restrict__ h){
  int bl = blockIdx.x; int b = bl >> 8; int l = bl & 255;
  int gh = l >> 4, gw = l & 15;
  __shared__ float xp[12]; __shared__ float tmp[128];
  int tid = threadIdx.x;  // block 384
  if (tid < 12){
    int ci = tid >> 2, ph = (tid >> 1) & 1, pw = tid & 1;
    xp[tid] = x[((size_t)(b*3 + ci)*32 + gh*2 + ph)*32 + gw*2 + pw];
  }
  __syncthreads();
  if (tid < 128){
    float a = 0.f;
    #pragma unroll
    for (int k = 0; k < 12; k++) a += xp[k] * pw1[tid*12 + k];
    tmp[tid] = a;
  }
  __syncthreads();
  float a = pb2[tid];
  for (int j = 0; j < 128; j++) a += tmp[j] * pw2[(size_t)tid*128 + j];
  h[(size_t)(b*256 + l)*384 + tid] = a + pos[(size_t)l*384 + tid];
}

// ---------- small linear ----------
__global__ void k_lin_small(const float* __restrict__ sc, const float* __restrict__ W,
                            const float* __restrict__ bias, float* __restrict__ out, int N){
  int idx = blockIdx.x * blockDim.x + threadIdx.x;
  if (idx >= 4*N) return;
  int b = idx / N, o = idx % N;
  const float4* cp = (const float4*)(sc + b*384);
  const float4* wp = (const float4*)(W + (size_t)o*384);
  float a = bias[o];
  #pragma unroll 4
  for (int k = 0; k < 96; k++){
    float4 c4 = cp[k], w4 = wp[k];
    a += c4.x*w4.x + c4.y*w4.y + c4.z*w4.z + c4.w*w4.w;
  }
  out[idx] = a;
}

// ---------- RMSNorm + adaLN modulate -> bf16 ----------
__global__ void k_rms_mod(const float* __restrict__ h, const float* __restrict__ nw,
                          const float* __restrict__ modBase, bf16_t* __restrict__ out){
  int bl = blockIdx.x; int b = bl >> 8;
  const float* hp = h + (size_t)bl*384;
  const float* mp = modBase + (size_t)b*18432;
  __shared__ float red[2];
  int tid = threadIdx.x;  // block 128
  float v[3]; float ss = 0.f;
  #pragma unroll
  for (int ii = 0; ii < 3; ii++){ v[ii] = hp[tid + ii*128]; ss += v[ii]*v[ii]; }
  #pragma unroll
  for (int off = 32; off; off >>= 1) ss += __shfl_down(ss, off);
  if ((tid & 63) == 0) red[tid >> 6] = ss;
  __syncthreads();
  ss = red[0] + red[1];
  float inv = rsqrtf(ss / 384.f + 1e-6f);
  #pragma unroll
  for (int ii = 0; ii < 3; ii++){
    int d = tid + ii*128;
    float xv = v[ii] * inv * nw[d];
    out[(size_t)bl*384 + d] = (bf16_t)(xv * (1.f + mp[384 + d]) + mp[d]);
  }
}

// ---------- bf16 MFMA GEMM: C[M,N] = A[M,K] @ W[N,K]^T ----------
// MODE 0: C = acc; MODE 1: C = acc + bias;
// MODE 2: C += gate*acc (gate = modBase[(row>>8)*18432 + col]);
// MODE 3: A-stage = bf16(silu(u1)*u2), A fp32 row stride 2K; C += gate*(acc+bias)
template<int MODE>
__global__ __launch_bounds__(256) void k_gemm_bf(
    const void* __restrict__ Avoid, const bf16_t* __restrict__ W,
    const float* __restrict__ bias, float* __restrict__ C,
    const float* __restrict__ modBase, int N, int K, int Nstore){
  __shared__ bf16_t As[2][64*40];
  __shared__ bf16_t Ws[2][64*40];
  const int tid = threadIdx.x;
  const int bm = blockIdx.y * 64, bn = blockIdx.x * 64;
  const int wave = tid >> 6, lane = tid & 63;
  const int m16 = lane & 15, kg = lane >> 4;
  const int r = tid >> 2, seg = tid & 3;
  const int nt = K / 32;

  uint4 aP, wP;
  auto loadT = [&](int kt){
    wP = *(const uint4*)(W + (size_t)(bn + r)*K + kt*32 + seg*8);
    if constexpr (MODE == 3){
      const float* Ap = (const float*)Avoid + (size_t)(bm + r)*(size_t)(2*K) + kt*32 + seg*8;
      float4 u1a = *(const float4*)(Ap),     u1b = *(const float4*)(Ap + 4);
      float4 u2a = *(const float4*)(Ap + K), u2b = *(const float4*)(Ap + K + 4);
      union { bf16_t h[8]; uint4 u; } pk;
      pk.h[0] = (bf16_t)(siluf(u1a.x)*u2a.x); pk.h[1] = (bf16_t)(siluf(u1a.y)*u2a.y);
      pk.h[2] = (bf16_t)(siluf(u1a.z)*u2a.z); pk.h[3] = (bf16_t)(siluf(u1a.w)*u2a.w);
      pk.h[4] = (bf16_t)(siluf(u1b.x)*u2b.x); pk.h[5] = (bf16_t)(siluf(u1b.y)*u2b.y);
      pk.h[6] = (bf16_t)(siluf(u1b.z)*u2b.z); pk.h[7] = (bf16_t)(siluf(u1b.w)*u2b.w);
      aP = pk.u;
    } else {
      aP = *(const uint4*)((const bf16_t*)Avoid + (size_t)(bm + r)*K + kt*32 + seg*8);
    }
  };
  auto stash = [&](int buf){
    *(uint4*)&As[buf][r*40 + seg*8] = aP;
    *(uint4*)&Ws[buf][r*40 + seg*8] = wP;
  };

  f32x4 acc[4] = {};
  loadT(0); stash(0); __syncthreads();
  for (int kt = 0; kt < nt; kt++){
    int buf = kt & 1;
    if (kt + 1 < nt) loadT(kt + 1);
    bf16x8 af = *(bf16x8*)&As[buf][(wave*16 + m16)*40 + kg*8];
    #pragma unroll
    for (int j = 0; j < 4; j++){
      bf16x8 bfr = *(bf16x8*)&Ws[buf][(j*16 + m16)*40 + kg*8];
      acc[j] = __builtin_amdgcn_mfma_f32_16x16x32_bf16(af, bfr, acc[j], 0, 0, 0);
    }
    if (kt + 1 < nt) stash(buf ^ 1);
    __syncthreads();
  }

  // C/D layout: col = lane&15, row = (lane>>4)*4 + reg
  #pragma unroll
  for (int j = 0; j < 4; j++){
    int col = bn + j*16 + m16;
    if (col < Nstore){
      #pragma unroll
      for (int rg = 0; rg < 4; rg++){
        int row = bm + wave*16 + kg*4 + rg;
        float v = acc[j][rg];
        if constexpr (MODE == 1 || MODE == 3) v += bias[col];
        if constexpr (MODE >= 2)
          C[(size_t)row*N + col] += modBase[(size_t)(row >> 8)*18432 + col] * v;
        else
          C[(size_t)row*N + col] = v;
      }
    }
  }
}

// ---------- depthwise 3x3 conv + bias + silu; writes fp32 + bf16 copies ----------
__global__ void k_conv(const float* __restrict__ z, const float* __restrict__ cw,
                       const float* __restrict__ cb, float* __restrict__ convT,
                       bf16_t* __restrict__ convB){
  int bl = blockIdx.x; int b = bl >> 8, l = bl & 255;
  int hh = l >> 4, ww = l & 15;
  int d = threadIdx.x;  // 384
  float acc = cb[d];
  #pragma unroll
  for (int kh = 0; kh < 3; kh++){
    int yy = hh + kh - 1; if ((unsigned)yy > 15u) continue;
    #pragma unroll
    for (int kw = 0; kw < 3; kw++){
      int xx = ww + kw - 1; if ((unsigned)xx > 15u) continue;
      acc += z[(size_t)(b*256 + yy*16 + xx)*384 + d] * cw[d*9 + kh*3 + kw];
    }
  }
  float s = siluf(acc);
  convT[(size_t)bl*384 + d] = s;
  convB[(size_t)bl*384 + d] = (bf16_t)s;
}

// ---------- fused dt + chunked selective scan -> ysT[b,k,d,l_scan] ----------
// xdblS layout: [b][lsp][224] cols k*56 + {dtr 0..23 | B 24..39 | C 40..55}
__global__ __launch_bounds__(256) void k_scan(
    const float* __restrict__ xdblS, const float* __restrict__ convT,
    const float* __restrict__ dtw, const float* __restrict__ dtb,
    const float* __restrict__ Alog, const float* __restrict__ Dsw,
    float* __restrict__ ysT){
  int blk = blockIdx.x;                 // b*1536 + k*384 + d
  int d = blk % 384; int k = (blk / 384) & 3; int b = blk / 1536;
  int tid = threadIdx.x;
  int n = tid & 15, chunk = tid >> 4;
  __shared__ float sdt[256], sxv[256], sy[256];
  __shared__ float sA[16][17], sB[16][17], sPre[16][17];

  // phase 0: dt[l] = softplus(dtr . dtw_row + dtb); stage x  (in-block: 384x L2 reuse)
  {
    int l = tid;
    int lp = perm_idx(k, l);
    const float4* xr = (const float4*)(xdblS + ((size_t)(b*256 + lp))*224 + k*56);
    const float4* w  = (const float4*)(dtw + ((size_t)k*384 + d)*24);
    float a = dtb[k*384 + d];
    #pragma unroll
    for (int r4 = 0; r4 < 6; r4++){
      float4 xv4 = xr[r4], wv4 = w[r4];
      a += xv4.x*wv4.x + xv4.y*wv4.y + xv4.z*wv4.z + xv4.w*wv4.w;
    }
    sdt[l] = softplusf(a);
    sxv[l] = convT[((size_t)(b*256 + lp))*384 + d];
  }
  __syncthreads();

  float a = -__expf(Alog[((size_t)(k*384) + d)*16 + n]);
  float Dv = Dsw[k*384 + d];

  // phase 1: local chunk scan from zero state
  float dA[16], dBu[16];
  float Ap = 1.f, hloc = 0.f;
  #pragma unroll
  for (int i = 0; i < 16; i++){
    int l = chunk*16 + i;
    int lp = perm_idx(k, l);
    float dtv = sdt[l];
    float bn = xdblS[((size_t)(b*256 + lp))*224 + k*56 + 24 + n];
    float e = __expf(dtv * a);
    float u = dtv * sxv[l] * bn;
    dA[i] = e; dBu[i] = u;
    Ap *= e; hloc = e*hloc + u;
  }
  sA[chunk][n] = Ap; sB[chunk][n] = hloc;
  __syncthreads();

  // phase 2: carry scan across 16 chunks
  if (tid < 16){
    float carry = 0.f;
    #pragma unroll
    for (int c = 0; c < 16; c++){
      sPre[c][tid] = carry;
      carry = sA[c][tid]*carry + sB[c][tid];
    }
  }
  __syncthreads();

  // phase 3: replay; reduce over n; stage into sy
  float h = sPre[chunk][n];
  #pragma unroll
  for (int i = 0; i < 16; i++){
    int l = chunk*16 + i;
    int lp = perm_idx(k, l);
    float cn = xdblS[((size_t)(b*256 + lp))*224 + k*56 + 40 + n];
    h = dA[i]*h + dBu[i];
    float p = h * cn;
    p += __shfl_xor(p, 1);
    p += __shfl_xor(p, 2);
    p += __shfl_xor(p, 4);
    p += __shfl_xor(p, 8);
    if (n == 0) sy[l] = p + Dv * sxv[l];
  }
  __syncthreads();
  // coalesced write: ysT[b,k,d,l]
  ysT[((size_t)(b*4 + k)*384 + d)*256 + tid] = sy[tid];
}

// ---------- merge 4 directions + LayerNorm(onorm) -> bf16 (ysT[b,k,d,l_scan]) ----------
__global__ void k_merge_ln(const float* __restrict__ ysT, const float* __restrict__ ow,
                           const float* __restrict__ ob, bf16_t* __restrict__ out){
  int bl = blockIdx.x; int b = bl >> 8; int l = bl & 255;
  int tl = ((l & 15) << 4) | (l >> 4);
  int i2 = 255 - l, i4 = 255 - tl;
  __shared__ float red[4];
  int tid = threadIdx.x;  // block 128
  const float* base = ysT + (size_t)b*4*384*256;
  float v[3]; float s = 0.f, s2 = 0.f;
  #pragma unroll
  for (int ii = 0; ii < 3; ii++){
    int d = tid + ii*128;
    float vv = base[(size_t)d*256 + l]
             + base[(size_t)(384 + d)*256 + i2]
             + base[(size_t)(768 + d)*256 + tl]
             + base[(size_t)(1152 + d)*256 + i4];
    v[ii] = vv; s += vv; s2 += vv*vv;
  }
  #pragma unroll
  for (int off = 32; off; off >>= 1){ s += __shfl_down(s, off); s2 += __shfl_down(s2, off); }
  if ((tid & 63) == 0){ red[tid >> 6] = s; red[2 + (tid >> 6)] = s2; }
  __syncthreads();
  s = red[0] + red[1]; s2 = red[2] + red[3];
  float mu = s / 384.f;
  float var = s2 / 384.f - mu*mu;
  float inv = rsqrtf(var + 1e-5f);
  #pragma unroll
  for (int ii = 0; ii < 3; ii++){
    int d = tid + ii*128;
    out[(size_t)bl*384 + d] = (bf16_t)((v[ii] - mu) * inv * ow[d] + ob[d]);
  }
}

// ---------- final: ln_na + modulate + f_lin + unpatchify ----------
__global__ void k_final(const float* __restrict__ h, const float* __restrict__ modf,
                        const float* __restrict__ flw, const float* __restrict__ flb,
                        float* __restrict__ out){
  int bl = blockIdx.x; int b = bl >> 8; int l = bl & 255;
  int tid = threadIdx.x;  // block 128
  __shared__ float buf[384]; __shared__ float red[4];
  const float* hp = h + (size_t)bl*384;
  float v[3]; float s = 0.f, s2 = 0.f;
  #pragma unroll
  for (int ii = 0; ii < 3; ii++){ float xv = hp[tid + ii*128]; v[ii] = xv; s += xv; s2 += xv*xv; }
  #pragma unroll
  for (int off = 32; off; off >>= 1){ s += __shfl_down(s, off); s2 += __shfl_down(s2, off); }
  if ((tid & 63) == 0){ red[tid >> 6] = s; red[2 + (tid >> 6)] = s2; }
  __syncthreads();
  s = red[0] + red[1]; s2 = red[2] + red[3];
  float mu = s / 384.f;
  float var = s2 / 384.f - mu*mu;
  float inv = rsqrtf(var + 1e-6f);
  #pragma unroll
  for (int ii = 0; ii < 3; ii++){
    int d = tid + ii*128;
    buf[d] = (v[ii] - mu) * inv * (1.f + modf[b*768 + 384 + d]) + modf[b*768 + d];
  }
  __syncthreads();
  if (tid < 12){
    float a = flb[tid];
    for (int k = 0; k < 384; k++) a += buf[k] * flw[(size_t)tid*384 + k];
    int p = tid / 6, q = (tid / 3) & 1, cc = tid % 3;
    int gh = l >> 4, gw = l & 15;
    out[((size_t)(b*3 + cc)*32 + gh*2 + p)*32 + gw*2 + q] = a;
  }
}

extern "C" void kernel_launch(void* const* d_in, const int* in_sizes, int n_in,
                              void* d_out, int out_size, void* d_ws, size_t ws_size,
                              hipStream_t stream){
  const float* x       = (const float*)d_in[0];
  const float* t       = (const float*)d_in[1];
  const int*   y       = (const int*)  d_in[2];
  const float* t_w1    = (const float*)d_in[3];
  const float* t_b1    = (const float*)d_in[4];
  const float* t_w2    = (const float*)d_in[5];
  const float* t_b2    = (const float*)d_in[6];
  const float* y_table = (const float*)d_in[7];
  const float* pe_w1   = (const float*)d_in[8];
  const float* pe_w2   = (const float*)d_in[9];
  const float* pe_b2   = (const float*)d_in[10];
  const float* pos     = (const float*)d_in[11];
  const float* adaln_w = (const float*)d_in[12];
  const float* adaln_b = (const float*)d_in[13];
  const float* n1_w    = (const float*)d_in[14];
  const float* n2_w    = (const float*)d_in[15];
  const float* in_w    = (const float*)d_in[16];
  const float* conv_w  = (const float*)d_in[17];
  const float* conv_b  = (const float*)d_in[18];
  const float* xproj_w = (const float*)d_in[19];
  const float* dt_w    = (const float*)d_in[20];
  const float* dt_b    = (const float*)d_in[21];
  const float* A_logs  = (const float*)d_in[22];
  const float* Ds      = (const float*)d_in[23];
  const float* onorm_w = (const float*)d_in[24];
  const float* onorm_b = (const float*)d_in[25];
  const float* outp_w  = (const float*)d_in[26];
  const float* mlp_w1  = (const float*)d_in[27];
  const float* mlp_b1  = (const float*)d_in[28];
  const float* mlp_w2  = (const float*)d_in[29];
  const float* mlp_b2  = (const float*)d_in[30];
  const float* f_adaln_w = (const float*)d_in[31];
  const float* f_adaln_b = (const float*)d_in[32];
  const float* f_lin_w = (const float*)d_in[33];
  const float* f_lin_b = (const float*)d_in[34];

  float* ws = (float*)d_ws;
  float*  sc      = ws + 0;         // 1536
  float*  h       = ws + 1536;      // 393216
  float*  modAll  = ws + 394752;    // 73728 (4 x 18432)
  float*  modf    = ws + 468480;    // 3072
  float*  buf1    = ws + 471552;    // 393216 (z)
  float*  convT   = ws + 864768;    // 393216
  float*  xdblS   = ws + 1257984;   // 229376 (4 x 256 x 224)
  float*  u12     = ws + 1487360;   // 3145728 (mlp intermediate)
  float*  ysT     = ws + 4633088;   // 1572864
  bf16_t* xin_bf  = (bf16_t*)(ws + 6205952);   // 393216 bf16
  bf16_t* ssin_bf = (bf16_t*)(ws + 6402560);   // 393216 bf16
  bf16_t* conv_bf = (bf16_t*)(ws + 6599168);   // 393216 bf16
  bf16_t* wbf     = (bf16_t*)(ws + 6795776);   // 2150400 bf16

  bf16_t* wbf_in = wbf;
  bf16_t* wbf_out = wbf + 147456;
  bf16_t* wbf_w1 = wbf + 294912;
  bf16_t* wbf_w2 = wbf + 1474560;
  bf16_t* wbf_xp = wbf + 2064384;

  k_cond<<<dim3(4), dim3(384), 0, stream>>>(t, y, t_w1, t_b1, t_w2, t_b2, y_table, sc);
  k_patch<<<dim3(1024), dim3(384), 0, stream>>>(x, pe_w1, pe_w2, pe_b2, pos, h);
  k_lin_small<<<dim3(288), dim3(256), 0, stream>>>(sc, adaln_w, adaln_b, modAll, 18432);

  for (int i = 0; i < 8; i++){
    const float* modL = modAll + (size_t)i*2304;
    k_cvt_layer<<<dim3(2100), dim3(256), 0, stream>>>(
        in_w + (size_t)i*147456, outp_w + (size_t)i*147456, mlp_w1 + (size_t)i*1179648,
        mlp_w2 + (size_t)i*589824, xproj_w + (size_t)i*86016, wbf);
    k_rms_mod<<<dim3(1024), dim3(128), 0, stream>>>(h, n1_w + i*384, modL + 0, xin_bf);
    k_gemm_bf<0><<<dim3(6,16), dim3(256), 0, stream>>>(
        xin_bf, wbf_in, nullptr, buf1, nullptr, 384, 384, 384);
    k_conv<<<dim3(1024), dim3(384), 0, stream>>>(
        buf1, conv_w + (size_t)i*384*9, conv_b + i*384, convT, conv_bf);
    k_gemm_bf<0><<<dim3(4,16), dim3(256), 0, stream>>>(
        conv_bf, wbf_xp, nullptr, xdblS, nullptr, 224, 384, 224);
    k_scan<<<dim3(6144), dim3(256), 0, stream>>>(
        xdblS, convT, dt_w + (size_t)i*4*384*24, dt_b + (size_t)i*4*384,
        A_logs + (size_t)i*4*384*16, Ds + (size_t)i*4*384, ysT);
    k_merge_ln<<<dim3(1024), dim3(128), 0, stream>>>(
        ysT, onorm_w + i*384, onorm_b + i*384, ssin_bf);
    k_gemm_bf<2><<<dim3(6,16), dim3(256), 0, stream>>>(
        ssin_bf, wbf_out, nullptr, h, modL + 768, 384, 384, 384);
    k_rms_mod<<<dim3(1024), dim3(128), 0, stream>>>(h, n2_w + i*384, modL + 1152, xin_bf);
    k_gemm_bf<1><<<dim3(48,16), dim3(256), 0, stream>>>(
        xin_bf, wbf_w1, mlp_b1 + (size_t)i*3072, u12, nullptr, 3072, 384, 3072);
    k_gemm_bf<3><<<dim3(6,16), dim3(256), 0, stream>>>(
        u12, wbf_w2, mlp_b2 + (size_t)i*384, h, modL + 1920, 384, 1536, 384);
  }

  k_lin_small<<<dim3(12), dim3(256), 0, stream>>>(sc, f_adaln_w, f_adaln_b, modf, 768);
  k_final<<<dim3(1024), dim3(128), 0, stream>>>(h, modf, f_lin_w, f_lin_b, (float*)d_out);
}